// Round 1
// baseline (90.319 us; speedup 1.0000x reference)
//
#include <hip/hip_runtime.h>

// IndexedLinearLayer: out[b,o] = sum_i x[b,i] * T[(idx[b,i]*SIZE_IN + i), o] + bias[o]
// B=512, SIZE_IN=1024, SIZE_OUT=256, NUM_Q=16.
//
// Structure: 1 block per batch row. 256 threads = 4 waves; wave w covers
// features [w*256, w*256+256). Lane l accumulates outputs [4l, 4l+4) via a
// float4 gather — 64 lanes * 16 B = one full 1 KB table row per wave-load,
// fully coalesced. x + row-offsets precomputed into LDS as packed int2 so the
// inner loop is one uniform ds_read_b64 + one global dwordx4 + 4 fp32 FMAs.

constexpr int BATCH    = 512;
constexpr int SIZE_IN  = 1024;
constexpr int SIZE_OUT = 256;

constexpr int THREADS    = 256;
constexpr int WAVES      = THREADS / 64;        // 4
constexpr int I_PER_WAVE = SIZE_IN / WAVES;     // 256

__global__ __launch_bounds__(THREADS, 2)
void indexed_linear_kernel(const float* __restrict__ x,      // [B, SIZE_IN]
                           const int*   __restrict__ idx,    // [B, SIZE_IN]
                           const float* __restrict__ table,  // [16*SIZE_IN, SIZE_OUT]
                           const float* __restrict__ bias,   // [SIZE_OUT]
                           float*       __restrict__ out)    // [B, SIZE_OUT]
{
    __shared__ int2  xr[SIZE_IN];             // {x bits, row element-offset} : 8 KB
    __shared__ float red[WAVES][SIZE_OUT];    // per-wave partials           : 4 KB

    const int b    = blockIdx.x;
    const int tid  = threadIdx.x;
    const int wave = tid >> 6;
    const int lane = tid & 63;

    // Stage x-row and precomputed table element-offsets into LDS (vectorized).
    {
        const float4 xv = reinterpret_cast<const float4*>(x   + b * SIZE_IN)[tid];
        const int4   qv = reinterpret_cast<const int4*>(idx + b * SIZE_IN)[tid];
        const int ibase = tid * 4;
        xr[ibase + 0] = make_int2(__float_as_int(xv.x), (qv.x * SIZE_IN + ibase + 0) * SIZE_OUT);
        xr[ibase + 1] = make_int2(__float_as_int(xv.y), (qv.y * SIZE_IN + ibase + 1) * SIZE_OUT);
        xr[ibase + 2] = make_int2(__float_as_int(xv.z), (qv.z * SIZE_IN + ibase + 2) * SIZE_OUT);
        xr[ibase + 3] = make_int2(__float_as_int(xv.w), (qv.w * SIZE_IN + ibase + 3) * SIZE_OUT);
    }
    __syncthreads();

    float4 acc = make_float4(0.f, 0.f, 0.f, 0.f);
    const int j0    = wave * I_PER_WAVE;
    const int olane = lane * 4;

    #pragma unroll 8
    for (int j = 0; j < I_PER_WAVE; ++j) {
        const int2  p  = xr[j0 + j];                  // uniform broadcast ds_read_b64
        const float xj = __int_as_float(p.x);
        const float4 w = *reinterpret_cast<const float4*>(table + p.y + olane);
        acc.x = fmaf(xj, w.x, acc.x);
        acc.y = fmaf(xj, w.y, acc.y);
        acc.z = fmaf(xj, w.z, acc.z);
        acc.w = fmaf(xj, w.w, acc.w);
    }

    *reinterpret_cast<float4*>(&red[wave][olane]) = acc;
    __syncthreads();

    // Final cross-wave reduce + bias; thread t owns output element t.
    float s = bias[tid];
    #pragma unroll
    for (int w = 0; w < WAVES; ++w) s += red[w][tid];
    out[b * SIZE_OUT + tid] = s;
}

extern "C" void kernel_launch(void* const* d_in, const int* in_sizes, int n_in,
                              void* d_out, int out_size, void* d_ws, size_t ws_size,
                              hipStream_t stream) {
    const float* x     = (const float*)d_in[0];
    const int*   idx   = (const int*)d_in[1];
    const float* table = (const float*)d_in[2];
    const float* bias  = (const float*)d_in[3];
    float*       out   = (float*)d_out;

    indexed_linear_kernel<<<dim3(BATCH), dim3(THREADS), 0, stream>>>(x, idx, table, bias, out);
}